// Round 4
// baseline (279.166 us; speedup 1.0000x reference)
//
#include <hip/hip_runtime.h>
#include <hip/hip_cooperative_groups.h>

namespace cg = cooperative_groups;

// ---------------- quantum gate appliers (16-amp statevector in regs) ----------------
// wire w -> bit position (3 - w); bit 3 is MSB of the flat index (row-major reshape).

__device__ __forceinline__ void apply_rx(float* sr, float* si, int bit, float c, float s) {
    const int m = 1 << bit;
#pragma unroll
    for (int idx = 0; idx < 16; ++idx) {
        if (idx & m) continue;
        const int j = idx | m;
        float a0r = sr[idx], a0i = si[idx], a1r = sr[j], a1i = si[j];
        // U = [[c, -i s], [-i s, c]]
        sr[idx] = c * a0r + s * a1i;
        si[idx] = c * a0i - s * a1r;
        sr[j]   = c * a1r + s * a0i;
        si[j]   = c * a1i - s * a0r;
    }
}

__device__ __forceinline__ void apply_ry(float* sr, float* si, int bit, float c, float s) {
    const int m = 1 << bit;
#pragma unroll
    for (int idx = 0; idx < 16; ++idx) {
        if (idx & m) continue;
        const int j = idx | m;
        float a0r = sr[idx], a0i = si[idx], a1r = sr[j], a1i = si[j];
        // U = [[c, -s], [s, c]]
        sr[idx] = c * a0r - s * a1r;
        si[idx] = c * a0i - s * a1i;
        sr[j]   = s * a0r + c * a1r;
        si[j]   = s * a0i + c * a1i;
    }
}

__device__ __forceinline__ void apply_rz(float* sr, float* si, int bit, float c, float s) {
    const int m = 1 << bit;
#pragma unroll
    for (int idx = 0; idx < 16; ++idx) {
        if (idx & m) continue;
        const int j = idx | m;
        float a0r = sr[idx], a0i = si[idx], a1r = sr[j], a1i = si[j];
        // diag(e^{-i t/2}, e^{+i t/2}) ; c = cos(t/2), s = sin(t/2)
        sr[idx] = c * a0r + s * a0i;
        si[idx] = c * a0i - s * a0r;
        sr[j]   = c * a1r - s * a1i;
        si[j]   = c * a1i + s * a1r;
    }
}

__device__ __forceinline__ void apply_cnot(float* sr, float* si, int cw, int tw) {
    const int cb = 3 - cw, tb = 3 - tw;
#pragma unroll
    for (int idx = 0; idx < 16; ++idx) {
        if (((idx >> cb) & 1) && !((idx >> tb) & 1)) {
            const int j = idx | (1 << tb);
            float tr = sr[idx]; sr[idx] = sr[j]; sr[j] = tr;
            float ti = si[idx]; si[idx] = si[j]; si[j] = ti;
        }
    }
}

// ---------------- kernel 1: pool (6x6 mean) + encode angles -> fp32 in d_out ----------------
// 8 samples/block, 256 threads, ~19 KB LDS -> 8 blocks/CU = 32 waves/CU.
// Staging now uses global_load_lds width=16 (no VGPR round-trip): each wave issues
// 4-5 x 1KB direct-to-LDS loads back-to-back; outstanding bytes/CU ~140KB >> the
// ~7KB Little's-law requirement for 6.3 TB/s. Compute phase verbatim from the
// harness-verified R1 kernel.

__global__ __launch_bounds__(256) void pool_angles_kernel(
    const float4* __restrict__ x,           // fp32 x viewed as float4 (144 per sample)
    const float* __restrict__ enc_w,        // [4,16]
    const float* __restrict__ enc_b,        // [4]
    float* __restrict__ angles_out)         // [B,4] fp32 (= d_out)
{
    __shared__ float4 xbuf[8 * 144];        // 18432 B, exact copy of 8 samples
    __shared__ float pooled[8][17];         // padded

    const int t = threadIdx.x;
    const int blk = blockIdx.x;

    // ---- stage 8 samples * 144 float4 = 1152 float4, direct global->LDS ----
    // LDS dest per wave = uniform base + lane*16 (linear), matching HW semantics.
    const float4* src = x + (size_t)blk * 1152;
#pragma unroll
    for (int j = 0; j < 4; ++j) {
        __builtin_amdgcn_global_load_lds(
            (const __attribute__((address_space(1))) void*)(src + t + 256 * j),
            (__attribute__((address_space(3))) void*)(&xbuf[t + 256 * j]),
            16, 0, 0);
    }
    if (t < 128) {
        __builtin_amdgcn_global_load_lds(
            (const __attribute__((address_space(1))) void*)(src + 1024 + t),
            (__attribute__((address_space(3))) void*)(&xbuf[1024 + t]),
            16, 0, 0);
    }
    __syncthreads();   // drains vmcnt before barrier (compiler-enforced)

    // ---- pooling: 256 threads = 8 samples x 16 cells x 2 halves (3 rows each) ----
    {
        const int s = t >> 5;               // sample 0..7
        const int q = t & 31;
        const int cell = q & 15;            // pool cell 0..15 (pr*4+pc)
        const int half = q >> 4;            // 0: rows 0-2, 1: rows 3-5
        const int pr = cell >> 2, pc = cell & 3;
        const float* sb = reinterpret_cast<const float*>(xbuf) + s * 576;
        const int base = pr * 144 + pc * 6 + half * 72;
        float acc = 0.0f;
        // row order rotated by pr to break pr-parity bank aliasing
#pragma unroll
        for (int r0 = 0; r0 < 3; ++r0) {
            int r = r0 + (pr & 3);
            if (r >= 3) r -= 3;
            const int rowbase = base + r * 24;
#pragma unroll
            for (int c = 0; c < 6; ++c)
                acc += sb[rowbase + c];
        }
        acc += __shfl_xor(acc, 16, 64);     // combine the two halves (same wave)
        if (half == 0)
            pooled[s][cell] = acc * (1.0f / 36.0f);
    }
    __syncthreads();

    // ---- angles: 32 threads, t -> (sample s = t>>2, angle i = t&3) ----
    if (t < 32) {
        const int s = t >> 2, i = t & 3;
        float a = enc_b[i];
#pragma unroll
        for (int k = 0; k < 16; ++k)
            a += enc_w[i * 16 + k] * pooled[s][k];
        angles_out[(blk * 8 + s) * 4 + i] = a;
    }
}

// ---------------- kernel 2 (cooperative): circuit + BN, z stays in registers ----------------
// 256 blocks x 256 threads = B threads, 1 block/CU -> trivially co-resident.
// Phase 1: angles -> circuit -> z[4] in regs -> block partials.
// Phase 2: grid.sync -> redundant reduce of 256x8 partials (L2) -> BN -> write out.
__global__ __launch_bounds__(256) void circuit_bn_coop(
    float4* __restrict__ io,                // [B] fp32 angle quads -> final out quads (= d_out)
    const float* __restrict__ var_params,   // [2,4,3] = 24
    const float* __restrict__ gamma,
    const float* __restrict__ beta,
    float* __restrict__ partials,           // [gridDim.x * 8]
    int B)
{
    __shared__ float gc[24], gs[24];
    __shared__ float red[4 * 8];
    __shared__ float stats[8];

    const int t = threadIdx.x;
    if (t < 24) {
        float th = 0.5f * var_params[t];
        float s, c;
        __sincosf(th, &s, &c);
        gc[t] = c; gs[t] = s;
    }
    __syncthreads();

    const int b = blockIdx.x * 256 + t;
    const float4 a4 = io[b];
    const float av[4] = {a4.x, a4.y, a4.z, a4.w};

    float sr[16], si[16];
#pragma unroll
    for (int i = 0; i < 16; ++i) { sr[i] = 0.0f; si[i] = 0.0f; }
    sr[0] = 1.0f;

#pragma unroll
    for (int w = 0; w < 4; ++w) {
        float s, c;
        __sincosf(0.5f * av[w], &s, &c);
        apply_rx(sr, si, 3 - w, c, s);
    }

#pragma unroll
    for (int d = 0; d < 2; ++d) {
#pragma unroll
        for (int w = 0; w < 4; ++w) {
            const int base = d * 12 + w * 3;
            apply_rx(sr, si, 3 - w, gc[base + 0], gs[base + 0]);
            apply_ry(sr, si, 3 - w, gc[base + 1], gs[base + 1]);
            apply_rz(sr, si, 3 - w, gc[base + 2], gs[base + 2]);
        }
        apply_cnot(sr, si, 0, 1);
        apply_cnot(sr, si, 1, 2);
        apply_cnot(sr, si, 2, 3);
        apply_cnot(sr, si, 3, 0);
    }

    float pr16[16];
#pragma unroll
    for (int i = 0; i < 16; ++i) pr16[i] = sr[i] * sr[i] + si[i] * si[i];

    float z[4];
#pragma unroll
    for (int w = 0; w < 4; ++w) {
        const int bit = 3 - w;
        float acc = 0.0f;
#pragma unroll
        for (int i = 0; i < 16; ++i)
            acc += ((i >> bit) & 1) ? -pr16[i] : pr16[i];
        z[w] = acc;
    }

    // block partials: sum(z), sum(z^2)
    float vals[8] = {z[0], z[1], z[2], z[3],
                     z[0] * z[0], z[1] * z[1], z[2] * z[2], z[3] * z[3]};
#pragma unroll
    for (int j = 0; j < 8; ++j) {
        float v = vals[j];
#pragma unroll
        for (int off = 32; off >= 1; off >>= 1)
            v += __shfl_down(v, off, 64);
        if ((t & 63) == 0) red[(t >> 6) * 8 + j] = v;
    }
    __syncthreads();
    if (t < 8)
        partials[blockIdx.x * 8 + t] = red[t] + red[8 + t] + red[16 + t] + red[24 + t];

    __threadfence();
    cg::this_grid().sync();

    // redundant reduce of 256 partial rows (8 KB, L2-resident)
    const int nRows = (int)gridDim.x;
    if (t < 64) {
        float part[8] = {0, 0, 0, 0, 0, 0, 0, 0};
        for (int r = t; r < nRows; r += 64) {
            const float* row = partials + r * 8;
#pragma unroll
            for (int j = 0; j < 8; ++j) part[j] += row[j];
        }
#pragma unroll
        for (int j = 0; j < 8; ++j) {
            float v = part[j];
#pragma unroll
            for (int off = 32; off >= 1; off >>= 1)
                v += __shfl_down(v, off, 64);
            if (t == 0) stats[j] = v;
        }
    }
    __syncthreads();

    // BN on register-resident z; single coalesced float4 store
    const float invB = 1.0f / (float)B;
    float res[4];
#pragma unroll
    for (int i = 0; i < 4; ++i) {
        const float mean = stats[i] * invB;
        float var = stats[4 + i] * invB - mean * mean;
        var = fmaxf(var, 0.0f);
        const float scale = gamma[i] * rsqrtf(var + 1e-5f);
        res[i] = (z[i] - mean) * scale + beta[i];
    }
    io[b] = make_float4(res[0], res[1], res[2], res[3]);
}

// ---------------- fallback split kernels (non-cooperative), verbatim R1 ----------------
__global__ __launch_bounds__(256) void circuit_kernel(
    float4* __restrict__ io,
    const float* __restrict__ var_params,
    float* __restrict__ partials)
{
    __shared__ float gc[24], gs[24];
    __shared__ float red[4 * 8];

    const int t = threadIdx.x;
    if (t < 24) {
        float th = 0.5f * var_params[t];
        float s, c;
        __sincosf(th, &s, &c);
        gc[t] = c; gs[t] = s;
    }
    __syncthreads();

    const int b = blockIdx.x * 256 + t;
    const float4 a4 = io[b];
    const float av[4] = {a4.x, a4.y, a4.z, a4.w};

    float sr[16], si[16];
#pragma unroll
    for (int i = 0; i < 16; ++i) { sr[i] = 0.0f; si[i] = 0.0f; }
    sr[0] = 1.0f;

#pragma unroll
    for (int w = 0; w < 4; ++w) {
        float s, c;
        __sincosf(0.5f * av[w], &s, &c);
        apply_rx(sr, si, 3 - w, c, s);
    }

#pragma unroll
    for (int d = 0; d < 2; ++d) {
#pragma unroll
        for (int w = 0; w < 4; ++w) {
            const int base = d * 12 + w * 3;
            apply_rx(sr, si, 3 - w, gc[base + 0], gs[base + 0]);
            apply_ry(sr, si, 3 - w, gc[base + 1], gs[base + 1]);
            apply_rz(sr, si, 3 - w, gc[base + 2], gs[base + 2]);
        }
        apply_cnot(sr, si, 0, 1);
        apply_cnot(sr, si, 1, 2);
        apply_cnot(sr, si, 2, 3);
        apply_cnot(sr, si, 3, 0);
    }

    float pr16[16];
#pragma unroll
    for (int i = 0; i < 16; ++i) pr16[i] = sr[i] * sr[i] + si[i] * si[i];

    float z[4];
#pragma unroll
    for (int w = 0; w < 4; ++w) {
        const int bit = 3 - w;
        float acc = 0.0f;
#pragma unroll
        for (int i = 0; i < 16; ++i)
            acc += ((i >> bit) & 1) ? -pr16[i] : pr16[i];
        z[w] = acc;
    }

    io[b] = make_float4(z[0], z[1], z[2], z[3]);

    float vals[8] = {z[0], z[1], z[2], z[3],
                     z[0] * z[0], z[1] * z[1], z[2] * z[2], z[3] * z[3]};
#pragma unroll
    for (int j = 0; j < 8; ++j) {
        float v = vals[j];
#pragma unroll
        for (int off = 32; off >= 1; off >>= 1)
            v += __shfl_down(v, off, 64);
        if ((t & 63) == 0) red[(t >> 6) * 8 + j] = v;
    }
    __syncthreads();
    if (t < 8)
        partials[blockIdx.x * 8 + t] = red[t] + red[8 + t] + red[16 + t] + red[24 + t];
}

__global__ __launch_bounds__(256) void bn_kernel(
    float4* __restrict__ io,
    const float* __restrict__ partials,
    const float* __restrict__ gamma,
    const float* __restrict__ beta,
    int nPartialRows, int B)
{
    __shared__ float stats[8];
    const int t = threadIdx.x;

    if (t < 64) {
        float part[8];
#pragma unroll
        for (int j = 0; j < 8; ++j) part[j] = 0.0f;
        for (int r = t; r < nPartialRows; r += 64) {
            const float* row = partials + r * 8;
#pragma unroll
            for (int j = 0; j < 8; ++j) part[j] += row[j];
        }
#pragma unroll
        for (int j = 0; j < 8; ++j) {
            float v = part[j];
#pragma unroll
            for (int off = 32; off >= 1; off >>= 1)
                v += __shfl_down(v, off, 64);
            if (t == 0) stats[j] = v;
        }
    }
    __syncthreads();

    const int b = blockIdx.x * 256 + t;
    const float invB = 1.0f / (float)B;
    const float4 z4 = io[b];
    const float zz[4] = {z4.x, z4.y, z4.z, z4.w};

    float res[4];
#pragma unroll
    for (int i = 0; i < 4; ++i) {
        const float mean = stats[i] * invB;
        float var = stats[4 + i] * invB - mean * mean;
        var = fmaxf(var, 0.0f);
        const float scale = gamma[i] * rsqrtf(var + 1e-5f);
        res[i] = (zz[i] - mean) * scale + beta[i];
    }
    io[b] = make_float4(res[0], res[1], res[2], res[3]);
}

// ---------------- launch ----------------
extern "C" void kernel_launch(void* const* d_in, const int* in_sizes, int n_in,
                              void* d_out, int out_size, void* d_ws, size_t ws_size,
                              hipStream_t stream) {
    const float4* x = (const float4*)d_in[0];
    const float* enc_w = (const float*)d_in[1];
    const float* enc_b = (const float*)d_in[2];
    const float* var_params = (const float*)d_in[3];
    const float* gamma = (const float*)d_in[4];
    const float* beta = (const float*)d_in[5];

    int B = in_sizes[0] / 576;                  // 65536
    float* io = (float*)d_out;                  // B*4 floats (angles -> out, in place)
    float* partials = (float*)d_ws;             // 256*8 floats

    const int nCircuitBlocks = B / 256;         // 256 -> 1 block/CU, co-resident

    // one-time co-residency check for the cooperative path (host query, graph-safe)
    static int mode = -1;
    if (mode < 0) {
        int maxActive = 0;
        hipError_t e = hipOccupancyMaxActiveBlocksPerMultiprocessor(
            &maxActive, circuit_bn_coop, 256, 0);
        int numCU = 0;
        hipDeviceGetAttribute(&numCU, hipDeviceAttributeMultiprocessorCount, 0);
        mode = (e == hipSuccess && numCU > 0 && maxActive * numCU >= nCircuitBlocks) ? 1 : 0;
    }

    pool_angles_kernel<<<B / 8, 256, 0, stream>>>(x, enc_w, enc_b, io);

    if (mode == 1) {
        float4* io4 = (float4*)io;
        void* args[] = {(void*)&io4, (void*)&var_params, (void*)&gamma, (void*)&beta,
                        (void*)&partials, (void*)&B};
        hipLaunchCooperativeKernel((const void*)circuit_bn_coop, dim3(nCircuitBlocks),
                                   dim3(256), args, 0, stream);
    } else {
        circuit_kernel<<<nCircuitBlocks, 256, 0, stream>>>((float4*)io, var_params, partials);
        bn_kernel<<<nCircuitBlocks, 256, 0, stream>>>((float4*)io, partials, gamma, beta,
                                                      nCircuitBlocks, B);
    }
}

// Round 5
// 238.985 us; speedup vs baseline: 1.1681x; 1.1681x over previous
//
#include <hip/hip_runtime.h>

// ---------------- quantum gate appliers (16-amp statevector in regs) ----------------
// wire w -> bit position (3 - w); bit 3 is MSB of the flat index (row-major reshape).

__device__ __forceinline__ void apply_rx(float* sr, float* si, int bit, float c, float s) {
    const int m = 1 << bit;
#pragma unroll
    for (int idx = 0; idx < 16; ++idx) {
        if (idx & m) continue;
        const int j = idx | m;
        float a0r = sr[idx], a0i = si[idx], a1r = sr[j], a1i = si[j];
        // U = [[c, -i s], [-i s, c]]
        sr[idx] = c * a0r + s * a1i;
        si[idx] = c * a0i - s * a1r;
        sr[j]   = c * a1r + s * a0i;
        si[j]   = c * a1i - s * a0r;
    }
}

__device__ __forceinline__ void apply_ry(float* sr, float* si, int bit, float c, float s) {
    const int m = 1 << bit;
#pragma unroll
    for (int idx = 0; idx < 16; ++idx) {
        if (idx & m) continue;
        const int j = idx | m;
        float a0r = sr[idx], a0i = si[idx], a1r = sr[j], a1i = si[j];
        // U = [[c, -s], [s, c]]
        sr[idx] = c * a0r - s * a1r;
        si[idx] = c * a0i - s * a1i;
        sr[j]   = s * a0r + c * a1r;
        si[j]   = s * a0i + c * a1i;
    }
}

__device__ __forceinline__ void apply_rz(float* sr, float* si, int bit, float c, float s) {
    const int m = 1 << bit;
#pragma unroll
    for (int idx = 0; idx < 16; ++idx) {
        if (idx & m) continue;
        const int j = idx | m;
        float a0r = sr[idx], a0i = si[idx], a1r = sr[j], a1i = si[j];
        // diag(e^{-i t/2}, e^{+i t/2}) ; c = cos(t/2), s = sin(t/2)
        sr[idx] = c * a0r + s * a0i;
        si[idx] = c * a0i - s * a0r;
        sr[j]   = c * a1r - s * a1i;
        si[j]   = c * a1i + s * a1r;
    }
}

__device__ __forceinline__ void apply_cnot(float* sr, float* si, int cw, int tw) {
    const int cb = 3 - cw, tb = 3 - tw;
#pragma unroll
    for (int idx = 0; idx < 16; ++idx) {
        if (((idx >> cb) & 1) && !((idx >> tb) & 1)) {
            const int j = idx | (1 << tb);
            float tr = sr[idx]; sr[idx] = sr[j]; sr[j] = tr;
            float ti = si[idx]; si[idx] = si[j]; si[j] = ti;
        }
    }
}

// ---------------- per-thread: pool-row q of sample s -> angles (4-lane butterfly) -> circuit -> z[4]
// Thread q of a 4-lane group streams the sample's pool-row q = image rows [6q, 6q+6)
// = 36 contiguous float4 (576 B, 9 full cache lines per lane). Pool-cell index
// ((4j+c)%24)/6 is COMPILE-TIME (no scratch). All 4 lanes get the full angles via
// shfl_xor butterfly and compute the circuit redundantly (branch-free, tiny vs stream).
// This device code is harness-verified (R3, absmax 0.0078).

__device__ __forceinline__ void pool_circuit(
    const float4* __restrict__ x,
    const float* __restrict__ enc_w,
    const float* __restrict__ enc_b,
    const float* __restrict__ var_params,
    int s, int q, float z[4])
{
    float pacc[4] = {0.0f, 0.0f, 0.0f, 0.0f};
    const float4* xs = x + (size_t)s * 144 + q * 36;
#pragma unroll
    for (int j = 0; j < 36; ++j) {
        const float4 v = xs[j];
        pacc[((4 * j + 0) % 24) / 6] += v.x;
        pacc[((4 * j + 1) % 24) / 6] += v.y;
        pacc[((4 * j + 2) % 24) / 6] += v.z;
        pacc[((4 * j + 3) % 24) / 6] += v.w;
    }

    // partial angles from this thread's 4 pool cells (k = 4q + pc)
    float pa[4];
#pragma unroll
    for (int i = 0; i < 4; ++i) {
        const float* wr = enc_w + i * 16 + q * 4;
        pa[i] = (wr[0] * pacc[0] + wr[1] * pacc[1] +
                 wr[2] * pacc[2] + wr[3] * pacc[3]) * (1.0f / 36.0f);
    }
    float av[4];
#pragma unroll
    for (int i = 0; i < 4; ++i) {
        float v = pa[i];
        v += __shfl_xor(v, 1, 64);
        v += __shfl_xor(v, 2, 64);
        av[i] = v + enc_b[i];
    }

    // gate tables (uniform params; compiler sinks sincos to use sites - R3: 44 VGPR)
    float gc[24], gs[24];
#pragma unroll
    for (int i = 0; i < 24; ++i) {
        float sn, cs;
        __sincosf(0.5f * var_params[i], &sn, &cs);
        gc[i] = cs; gs[i] = sn;
    }

    // statevector simulation, all in registers
    float sr[16], si[16];
#pragma unroll
    for (int i = 0; i < 16; ++i) { sr[i] = 0.0f; si[i] = 0.0f; }
    sr[0] = 1.0f;

#pragma unroll
    for (int w = 0; w < 4; ++w) {
        float sn, cs;
        __sincosf(0.5f * av[w], &sn, &cs);
        apply_rx(sr, si, 3 - w, cs, sn);
    }

#pragma unroll
    for (int d = 0; d < 2; ++d) {
#pragma unroll
        for (int w = 0; w < 4; ++w) {
            const int base = d * 12 + w * 3;
            apply_rx(sr, si, 3 - w, gc[base + 0], gs[base + 0]);
            apply_ry(sr, si, 3 - w, gc[base + 1], gs[base + 1]);
            apply_rz(sr, si, 3 - w, gc[base + 2], gs[base + 2]);
        }
        apply_cnot(sr, si, 0, 1);
        apply_cnot(sr, si, 1, 2);
        apply_cnot(sr, si, 2, 3);
        apply_cnot(sr, si, 3, 0);
    }

    float pr16[16];
#pragma unroll
    for (int i = 0; i < 16; ++i) pr16[i] = sr[i] * sr[i] + si[i] * si[i];

#pragma unroll
    for (int w = 0; w < 4; ++w) {
        const int bit = 3 - w;
        float acc = 0.0f;
#pragma unroll
        for (int i = 0; i < 16; ++i)
            acc += ((i >> bit) & 1) ? -pr16[i] : pr16[i];
        z[w] = acc;
    }
}

// ---------------- kernel 1: fused pool+circuit (PLAIN launch, no grid sync) ----------------
// 1024 blocks x 256 threads, 4 threads/sample -> 16 waves/CU. Writes z coalesced
// (scalar float per thread, 1 KB/wave contiguous) + per-block BN partials.
__global__ __launch_bounds__(256, 4) void fused_pc(
    const float4* __restrict__ x,
    const float* __restrict__ enc_w, const float* __restrict__ enc_b,
    const float* __restrict__ var_params,
    float* __restrict__ out_z,        // [B*4] fp32 z (= d_out, finalized in place by BN)
    float* __restrict__ partials)     // [gridDim.x * 8]
{
    __shared__ float red[4 * 8];
    const int t = threadIdx.x;
    const int s = blockIdx.x * 64 + (t >> 2);
    const int q = t & 3;

    float z[4];
    pool_circuit(x, enc_w, enc_b, var_params, s, q, z);
    out_z[blockIdx.x * 256 + t] = z[q];         // element index = s*4+q, coalesced

    // block partials: sum(z), sum(z^2); every lane holds z (x4 redundant -> scale 0.25)
    float vals[8] = {z[0], z[1], z[2], z[3],
                     z[0] * z[0], z[1] * z[1], z[2] * z[2], z[3] * z[3]};
#pragma unroll
    for (int j = 0; j < 8; ++j) {
        float v = vals[j];
#pragma unroll
        for (int off = 32; off >= 1; off >>= 1)
            v += __shfl_down(v, off, 64);
        if ((t & 63) == 0) red[(t >> 6) * 8 + j] = v;
    }
    __syncthreads();
    if (t < 8)
        partials[blockIdx.x * 8 + t] =
            0.25f * (red[t] + red[8 + t] + red[16 + t] + red[24 + t]);
}

// ---------------- kernel 2: batchnorm finalize; fp32 z -> fp32 out (in place) ----------------
// Verbatim from the harness-verified R1 kernel.
__global__ __launch_bounds__(256) void bn_kernel(
    float4* __restrict__ io,                // [B] fp32 z quads -> out quads (= d_out)
    const float* __restrict__ partials,     // [nPartialRows * 8]
    const float* __restrict__ gamma,
    const float* __restrict__ beta,
    int nPartialRows, int B)
{
    __shared__ float stats[8];
    const int t = threadIdx.x;

    if (t < 64) {
        float part[8];
#pragma unroll
        for (int j = 0; j < 8; ++j) part[j] = 0.0f;
        for (int r = t; r < nPartialRows; r += 64) {
            const float* row = partials + r * 8;
#pragma unroll
            for (int j = 0; j < 8; ++j) part[j] += row[j];
        }
#pragma unroll
        for (int j = 0; j < 8; ++j) {
            float v = part[j];
#pragma unroll
            for (int off = 32; off >= 1; off >>= 1)
                v += __shfl_down(v, off, 64);
            if (t == 0) stats[j] = v;
        }
    }
    __syncthreads();

    const int b = blockIdx.x * 256 + t;
    const float invB = 1.0f / (float)B;
    const float4 z4 = io[b];
    const float zz[4] = {z4.x, z4.y, z4.z, z4.w};

    float res[4];
#pragma unroll
    for (int i = 0; i < 4; ++i) {
        const float mean = stats[i] * invB;
        float var = stats[4 + i] * invB - mean * mean;
        var = fmaxf(var, 0.0f);
        const float scale = gamma[i] * rsqrtf(var + 1e-5f);
        res[i] = (zz[i] - mean) * scale + beta[i];
    }
    io[b] = make_float4(res[0], res[1], res[2], res[3]);
}

// ---------------- launch ----------------
extern "C" void kernel_launch(void* const* d_in, const int* in_sizes, int n_in,
                              void* d_out, int out_size, void* d_ws, size_t ws_size,
                              hipStream_t stream) {
    const float4* x = (const float4*)d_in[0];
    const float* enc_w = (const float*)d_in[1];
    const float* enc_b = (const float*)d_in[2];
    const float* var_params = (const float*)d_in[3];
    const float* gamma = (const float*)d_in[4];
    const float* beta = (const float*)d_in[5];

    int B = in_sizes[0] / 576;                  // 65536
    float* out = (float*)d_out;                 // B*4 floats (z -> out, in place)
    float* partials = (float*)d_ws;             // nBlocks*8 floats = 32 KB

    const int nBlocks = B / 64;                 // 1024

    fused_pc<<<nBlocks, 256, 0, stream>>>(x, enc_w, enc_b, var_params, out, partials);
    bn_kernel<<<B / 256, 256, 0, stream>>>((float4*)out, partials, gamma, beta,
                                           nBlocks, B);
}

// Round 6
// 227.688 us; speedup vs baseline: 1.2261x; 1.0496x over previous
//
#include <hip/hip_runtime.h>

// ---------------- quantum gate appliers (16-amp statevector in regs) ----------------
// wire w -> bit position (3 - w); bit 3 is MSB of the flat index (row-major reshape).

__device__ __forceinline__ void apply_rx(float* sr, float* si, int bit, float c, float s) {
    const int m = 1 << bit;
#pragma unroll
    for (int idx = 0; idx < 16; ++idx) {
        if (idx & m) continue;
        const int j = idx | m;
        float a0r = sr[idx], a0i = si[idx], a1r = sr[j], a1i = si[j];
        // U = [[c, -i s], [-i s, c]]
        sr[idx] = c * a0r + s * a1i;
        si[idx] = c * a0i - s * a1r;
        sr[j]   = c * a1r + s * a0i;
        si[j]   = c * a1i - s * a0r;
    }
}

__device__ __forceinline__ void apply_ry(float* sr, float* si, int bit, float c, float s) {
    const int m = 1 << bit;
#pragma unroll
    for (int idx = 0; idx < 16; ++idx) {
        if (idx & m) continue;
        const int j = idx | m;
        float a0r = sr[idx], a0i = si[idx], a1r = sr[j], a1i = si[j];
        // U = [[c, -s], [s, c]]
        sr[idx] = c * a0r - s * a1r;
        si[idx] = c * a0i - s * a1i;
        sr[j]   = s * a0r + c * a1r;
        si[j]   = s * a0i + c * a1i;
    }
}

__device__ __forceinline__ void apply_rz(float* sr, float* si, int bit, float c, float s) {
    const int m = 1 << bit;
#pragma unroll
    for (int idx = 0; idx < 16; ++idx) {
        if (idx & m) continue;
        const int j = idx | m;
        float a0r = sr[idx], a0i = si[idx], a1r = sr[j], a1i = si[j];
        // diag(e^{-i t/2}, e^{+i t/2}) ; c = cos(t/2), s = sin(t/2)
        sr[idx] = c * a0r + s * a0i;
        si[idx] = c * a0i - s * a0r;
        sr[j]   = c * a1r - s * a1i;
        si[j]   = c * a1i + s * a1r;
    }
}

__device__ __forceinline__ void apply_cnot(float* sr, float* si, int cw, int tw) {
    const int cb = 3 - cw, tb = 3 - tw;
#pragma unroll
    for (int idx = 0; idx < 16; ++idx) {
        if (((idx >> cb) & 1) && !((idx >> tb) & 1)) {
            const int j = idx | (1 << tb);
            float tr = sr[idx]; sr[idx] = sr[j]; sr[j] = tr;
            float ti = si[idx]; si[idx] = si[j]; si[j] = ti;
        }
    }
}

// direct global->LDS, width 16 (syntax harness-verified in R4)
#define GLLDS(gp, lp)                                                          \
    __builtin_amdgcn_global_load_lds(                                          \
        (const __attribute__((address_space(1))) void*)(gp),                   \
        (__attribute__((address_space(3))) void*)(lp), 16, 0, 0)

// ---------------- pool + angles for one 8-sample tile (R1 math, verbatim) ----------------
// Internal barrier is lgkmcnt-only + raw s_barrier so in-flight global_load_lds
// for the NEXT tile is not drained.
__device__ __forceinline__ void pool_tile_angles(
    const float4* __restrict__ xbuf_tile,   // [1152] staged tile (8 samples)
    float (*pooled)[17],
    const float* __restrict__ enc_w,
    const float* __restrict__ enc_b,
    float* __restrict__ angles_out,
    int sampleBase, int t)
{
    // ---- pooling: 256 threads = 8 samples x 16 cells x 2 halves (3 rows each) ----
    {
        const int s = t >> 5;               // sample 0..7
        const int q = t & 31;
        const int cell = q & 15;            // pool cell 0..15 (pr*4+pc)
        const int half = q >> 4;            // 0: rows 0-2, 1: rows 3-5
        const int pr = cell >> 2, pc = cell & 3;
        const float* sb = reinterpret_cast<const float*>(xbuf_tile) + s * 576;
        const int base = pr * 144 + pc * 6 + half * 72;
        float acc = 0.0f;
        // row order rotated by pr to break pr-parity bank aliasing
#pragma unroll
        for (int r0 = 0; r0 < 3; ++r0) {
            int r = r0 + (pr & 3);
            if (r >= 3) r -= 3;
            const int rowbase = base + r * 24;
#pragma unroll
            for (int c = 0; c < 6; ++c)
                acc += sb[rowbase + c];
        }
        acc += __shfl_xor(acc, 16, 64);     // combine the two halves (same wave)
        if (half == 0)
            pooled[s][cell] = acc * (1.0f / 36.0f);
    }
    // lgkm-only barrier: pooled visible without draining vmcnt (next tile in flight)
    asm volatile("s_waitcnt lgkmcnt(0)" ::: "memory");
    __builtin_amdgcn_sched_barrier(0);
    __builtin_amdgcn_s_barrier();

    // ---- angles: 32 threads, t -> (sample s = t>>2, angle i = t&3) ----
    if (t < 32) {
        const int s = t >> 2, i = t & 3;
        float a = enc_b[i];
#pragma unroll
        for (int k = 0; k < 16; ++k)
            a += enc_w[i * 16 + k] * pooled[s][k];
        angles_out[(sampleBase + s) * 4 + i] = a;
    }
}

// ---------------- kernel 1: double-buffered pool+angles ----------------
// 16 samples/block as two 8-sample tiles; 37 KB LDS -> 4 blocks/CU = 16 waves/CU.
// Issue A loads, issue B loads (order pinned), wait vmcnt(4) (= A landed, B in
// flight), raw barrier, pool A while B flies, vmcnt(0)+barrier, pool B.
__global__ __launch_bounds__(256) void pool_angles_db(
    const float4* __restrict__ x,           // fp32 x viewed as float4 (144 per sample)
    const float* __restrict__ enc_w,        // [4,16]
    const float* __restrict__ enc_b,        // [4]
    float* __restrict__ angles_out)         // [B,4] fp32 (= d_out)
{
    __shared__ float4 xbuf[2][1152];        // 2 x 18432 B
    __shared__ float pooled[8][17];         // padded; reused across tiles (barrier-protected)

    const int t = threadIdx.x;
    const int blk = blockIdx.x;
    const float4* srcA = x + (size_t)blk * 2304;
    const float4* srcB = srcA + 1152;

    // ---- issue tile A stage (4-5 gl_lds per thread; wave-uniform counts) ----
#pragma unroll
    for (int j = 0; j < 4; ++j)
        GLLDS(srcA + t + 256 * j, &xbuf[0][t + 256 * j]);
    if (t < 128)
        GLLDS(srcA + 1024 + t, &xbuf[0][1024 + t]);
    __builtin_amdgcn_sched_barrier(0);      // pin: all A-loads issued before B-loads

    // ---- issue tile B stage ----
#pragma unroll
    for (int j = 0; j < 4; ++j)
        GLLDS(srcB + t + 256 * j, &xbuf[1][t + 256 * j]);
    if (t < 128)
        GLLDS(srcB + 1024 + t, &xbuf[1][1024 + t]);
    __builtin_amdgcn_sched_barrier(0);

    // ---- counted drain: oldest (A) loads retired; >=4 B-loads stay in flight ----
    asm volatile("s_waitcnt vmcnt(4)" ::: "memory");
    __builtin_amdgcn_sched_barrier(0);
    __builtin_amdgcn_s_barrier();

    pool_tile_angles(xbuf[0], pooled, enc_w, enc_b, angles_out, blk * 16, t);

    // ---- drain B (and the tiny angle store), then pool B ----
    asm volatile("s_waitcnt vmcnt(0)" ::: "memory");
    __builtin_amdgcn_sched_barrier(0);
    __builtin_amdgcn_s_barrier();

    pool_tile_angles(xbuf[1], pooled, enc_w, enc_b, angles_out, blk * 16 + 8, t);
}

// ---------------- kernel 2: circuit sim; fp32 angles -> fp32 z (in place) + BN partials ----------------
// Verbatim from the harness-verified R1 kernel.
__global__ __launch_bounds__(256) void circuit_kernel(
    float4* __restrict__ io,                // [B] fp32 angle quads -> fp32 z quads (= d_out)
    const float* __restrict__ var_params,   // [2,4,3] = 24
    float* __restrict__ partials)           // [gridDim.x * 8]
{
    __shared__ float gc[24], gs[24];
    __shared__ float red[4 * 8];

    const int t = threadIdx.x;
    if (t < 24) {
        float th = 0.5f * var_params[t];
        float s, c;
        __sincosf(th, &s, &c);
        gc[t] = c; gs[t] = s;
    }
    __syncthreads();

    const int b = blockIdx.x * 256 + t;
    const float4 a4 = io[b];
    const float av[4] = {a4.x, a4.y, a4.z, a4.w};

    float sr[16], si[16];
#pragma unroll
    for (int i = 0; i < 16; ++i) { sr[i] = 0.0f; si[i] = 0.0f; }
    sr[0] = 1.0f;

#pragma unroll
    for (int w = 0; w < 4; ++w) {
        float s, c;
        __sincosf(0.5f * av[w], &s, &c);
        apply_rx(sr, si, 3 - w, c, s);
    }

#pragma unroll
    for (int d = 0; d < 2; ++d) {
#pragma unroll
        for (int w = 0; w < 4; ++w) {
            const int base = d * 12 + w * 3;
            apply_rx(sr, si, 3 - w, gc[base + 0], gs[base + 0]);
            apply_ry(sr, si, 3 - w, gc[base + 1], gs[base + 1]);
            apply_rz(sr, si, 3 - w, gc[base + 2], gs[base + 2]);
        }
        apply_cnot(sr, si, 0, 1);
        apply_cnot(sr, si, 1, 2);
        apply_cnot(sr, si, 2, 3);
        apply_cnot(sr, si, 3, 0);
    }

    float pr16[16];
#pragma unroll
    for (int i = 0; i < 16; ++i) pr16[i] = sr[i] * sr[i] + si[i] * si[i];

    float z[4];
#pragma unroll
    for (int w = 0; w < 4; ++w) {
        const int bit = 3 - w;
        float acc = 0.0f;
#pragma unroll
        for (int i = 0; i < 16; ++i)
            acc += ((i >> bit) & 1) ? -pr16[i] : pr16[i];
        z[w] = acc;
    }

    io[b] = make_float4(z[0], z[1], z[2], z[3]);

    float vals[8] = {z[0], z[1], z[2], z[3],
                     z[0] * z[0], z[1] * z[1], z[2] * z[2], z[3] * z[3]};
#pragma unroll
    for (int j = 0; j < 8; ++j) {
        float v = vals[j];
#pragma unroll
        for (int off = 32; off >= 1; off >>= 1)
            v += __shfl_down(v, off, 64);
        if ((t & 63) == 0) red[(t >> 6) * 8 + j] = v;
    }
    __syncthreads();
    if (t < 8)
        partials[blockIdx.x * 8 + t] = red[t] + red[8 + t] + red[16 + t] + red[24 + t];
}

// ---------------- kernel 3: batchnorm finalize; fp32 z -> fp32 out (in place) ----------------
// Verbatim from the harness-verified R1 kernel.
__global__ __launch_bounds__(256) void bn_kernel(
    float4* __restrict__ io,                // [B] fp32 z quads -> out quads (= d_out)
    const float* __restrict__ partials,     // [nPartialRows * 8]
    const float* __restrict__ gamma,
    const float* __restrict__ beta,
    int nPartialRows, int B)
{
    __shared__ float stats[8];
    const int t = threadIdx.x;

    if (t < 64) {
        float part[8];
#pragma unroll
        for (int j = 0; j < 8; ++j) part[j] = 0.0f;
        for (int r = t; r < nPartialRows; r += 64) {
            const float* row = partials + r * 8;
#pragma unroll
            for (int j = 0; j < 8; ++j) part[j] += row[j];
        }
#pragma unroll
        for (int j = 0; j < 8; ++j) {
            float v = part[j];
#pragma unroll
            for (int off = 32; off >= 1; off >>= 1)
                v += __shfl_down(v, off, 64);
            if (t == 0) stats[j] = v;
        }
    }
    __syncthreads();

    const int b = blockIdx.x * 256 + t;
    const float invB = 1.0f / (float)B;
    const float4 z4 = io[b];
    const float zz[4] = {z4.x, z4.y, z4.z, z4.w};

    float res[4];
#pragma unroll
    for (int i = 0; i < 4; ++i) {
        const float mean = stats[i] * invB;
        float var = stats[4 + i] * invB - mean * mean;
        var = fmaxf(var, 0.0f);
        const float scale = gamma[i] * rsqrtf(var + 1e-5f);
        res[i] = (zz[i] - mean) * scale + beta[i];
    }
    io[b] = make_float4(res[0], res[1], res[2], res[3]);
}

// ---------------- launch ----------------
extern "C" void kernel_launch(void* const* d_in, const int* in_sizes, int n_in,
                              void* d_out, int out_size, void* d_ws, size_t ws_size,
                              hipStream_t stream) {
    const float4* x = (const float4*)d_in[0];
    const float* enc_w = (const float*)d_in[1];
    const float* enc_b = (const float*)d_in[2];
    const float* var_params = (const float*)d_in[3];
    const float* gamma = (const float*)d_in[4];
    const float* beta = (const float*)d_in[5];

    const int B = in_sizes[0] / 576;            // 65536
    float* io = (float*)d_out;                  // B*4 floats (angles -> z -> out, in place)
    float* partials = (float*)d_ws;             // 256*8 floats

    const int nCircuitBlocks = B / 256;         // 256

    pool_angles_db<<<B / 16, 256, 0, stream>>>(x, enc_w, enc_b, io);
    circuit_kernel<<<nCircuitBlocks, 256, 0, stream>>>((float4*)io, var_params, partials);
    bn_kernel<<<nCircuitBlocks, 256, 0, stream>>>((float4*)io, partials, gamma, beta,
                                                  nCircuitBlocks, B);
}